// Round 5
// baseline (551.968 us; speedup 1.0000x reference)
//
#include <hip/hip_runtime.h>
#include <math.h>

#define WT_LEN 512
#define N_WT 20
#define B_ 16
#define T_ 262144           // 2^18 per row
#define TOTAL (B_ * T_)     // 4194304
#define CHUNK 8192          // 2^13 elems per block
#define NCHR 32             // chunks per row
#define NCH  512            // total chunks

// inc = (pitch / 44100) * 512 ; f32 division correctly rounded (verified R1/R2).
__device__ __forceinline__ float to_inc1(float x) {
    return (x / 44100.0f) * 512.0f;
}
__device__ __forceinline__ float4 to_inc4(float4 p) {
    float4 r;
    r.x = to_inc1(p.x); r.y = to_inc1(p.y);
    r.z = to_inc1(p.z); r.w = to_inc1(p.w);
    return r;
}

// ---------------------------------------------------------------------------
// U: per-chunk exact adjacent-pair tree reduction -> A13[chunk]. (unchanged)
// ---------------------------------------------------------------------------
__global__ __launch_bounds__(1024) void up_kernel(
        const float* __restrict__ pitch, float* __restrict__ A13) {
    __shared__ float red[2048];
    const int t = threadIdx.x;
    const size_t g0 = (size_t)blockIdx.x * CHUNK;

    const float4* p4 = (const float4*)(pitch + g0);
    float4 v0 = to_inc4(p4[2 * t]);
    float4 v1 = to_inc4(p4[2 * t + 1]);
    float t0 = v0.x + v0.y, t1 = v0.z + v0.w;
    float t2 = v1.x + v1.y, t3 = v1.z + v1.w;
    red[t] = (t0 + t1) + (t2 + t3);        // A3[t]
    __syncthreads();
    int off_prev = 0, off = 1024;
    for (int sz = 512; sz >= 1; sz >>= 1) {   // levels 4..13
        if (t < sz) red[off + t] = red[off_prev + 2 * t] + red[off_prev + 2 * t + 1];
        __syncthreads();
        off_prev = off; off += sz;
    }
    if (t == 0) A13[blockIdx.x] = red[2046];
}

// ---------------------------------------------------------------------------
// Compact, bit-exact evaluation of mid's odd-even scan. (unchanged)
// ---------------------------------------------------------------------------
__device__ __forceinline__ float l1f(const float* A, int m) { return A[2*m] + A[2*m+1]; }
__device__ __forceinline__ float l2f(const float* A, int m) { return l1f(A,2*m) + l1f(A,2*m+1); }
__device__ __forceinline__ float l3f(const float* A, int m) { return l2f(A,2*m) + l2f(A,2*m+1); }
__device__ __forceinline__ float l4f(const float* A, int m) { return l3f(A,2*m) + l3f(A,2*m+1); }

__device__ float s0_of(const float* __restrict__ A, int j) {
    if (j == 0) return A[0];
    float p0 = 0.f, p1 = 0.f, p2 = 0.f, p3 = 0.f;
    bool h0 = false, h1 = false, h2 = false, h3 = false;
    float base;
    int m = j;
    if ((m & 1) == 0) { p0 = A[m]; h0 = true; m = (m - 2) >> 1; }
    else m >>= 1;
    if (m == 0) { base = l1f(A, 0); goto comb; }
    if ((m & 1) == 0) { p1 = l1f(A, m); h1 = true; m = (m - 2) >> 1; }
    else m >>= 1;
    if (m == 0) { base = l2f(A, 0); goto comb; }
    if ((m & 1) == 0) { p2 = l2f(A, m); h2 = true; m = (m - 2) >> 1; }
    else m >>= 1;
    if (m == 0) { base = l3f(A, 0); goto comb; }
    if ((m & 1) == 0) { p3 = l3f(A, m); h3 = true; m = (m - 2) >> 1; }
    else m >>= 1;
    base = (m == 0) ? l4f(A, 0) : (l4f(A, 0) + l4f(A, 1));   // s4[0] / s4[1]=l5
comb:
    if (h3) base += p3;
    if (h2) base += p2;
    if (h1) base += p1;
    if (h0) base += p0;
    return base;
}

// ---------------------------------------------------------------------------
// D v3: self-sufficient exact scan (unchanged from R3's passing version).
// ---------------------------------------------------------------------------
__global__ __launch_bounds__(1024, 8) void down_kernel(
        const float* __restrict__ pitch, const float* __restrict__ A13,
        float* __restrict__ sout) {
    __shared__ float a[2048];       // levels 3..13
    const int t = threadIdx.x;
    const int c = blockIdx.x;
    const size_t g0 = (size_t)c * CHUNK;

    float P = 0.0f, T13 = 0.0f;
    if (t == 0) {
        const float* A = A13 + ((c >> 5) << 5);   // this row's 32 chunk totals
        const int lc = c & (NCHR - 1);
        if (lc) P = s0_of(A, lc - 1);
        T13 = s0_of(A, lc);
    }

    const float4* p4 = (const float4*)(pitch + g0);
    float4 va = to_inc4(p4[2 * t]);
    float4 vb = to_inc4(p4[2 * t + 1]);
    float x0 = va.x, x2 = va.z, x4 = vb.x, x6 = vb.z;
    float t0 = va.x + va.y, t1 = va.z + va.w;
    float t2 = vb.x + vb.y, t3 = vb.z + vb.w;
    float u0 = t0 + t1, u1 = t2 + t3;
    a[t] = u0 + u1;                 // A3[t]
    __syncthreads();

    int bp = 0, b = 1024;
    for (int sz = 512; sz >= 2; sz >>= 1) {
        if (t < sz) a[b + t] = a[bp + 2 * t] + a[bp + 2 * t + 1];
        __syncthreads();
        bp = b; b += sz;
    }

    if (t == 0) {
        a[2044] = P + a[2044];      // s12[0] = P + A12[0]
        a[2045] = T13;              // s12[1] = S13[c]
    }
    __syncthreads();

    const int offk[10] = {0, 1024, 1536, 1792, 1920, 1984, 2016, 2032, 2040, 2044};
    for (int k = 11; k >= 3; --k) {
        int m = 1 << (13 - k), half = m >> 1;
        int bk = offk[k - 3], bn = offk[k - 2];
        if (t < half) {
            float sn = a[bn + t];                  // s_{k+1}[t], finalized
            int j = 2 * t + 2;
            float av = (j < m) ? a[bk + j] : 0.0f;
            a[bk + 2 * t + 1] = sn;
            if (j < m) a[bk + j] = sn + av;
        }
        if (t == 0) a[bk] = P + a[bk];             // s_k[0]
        __syncthreads();
    }

    float S3prev = t ? a[t - 1] : P;
    float s3t = a[t];
    float s1a = S3prev + t0;        // s1[4t]
    float s2a = S3prev + u0;        // s2[2t]
    float s1c = s2a + t2;           // s1[4t+2]
    (void)t1; (void)t3; (void)u1;

    float4* q4 = (float4*)(sout + g0);
    q4[2 * t]     = make_float4(S3prev + x0, s1a, s1a + x2, s2a);
    q4[2 * t + 1] = make_float4(s2a + x4, s1c, s1c + x6, s3t);
}

// ---------------------------------------------------------------------------
// mix v4 (byte-identical math to R4's passing version). Idempotent:
// reads S/pitch/amp/att/wtg, writes out. Launched twice this round — second
// launch with grid 256 is a DIAGNOSTIC (runs ~4x longer -> forced into the
// rocprof top-5 so we finally see mix's FETCH/WRITE/LDS_CONFLICT/VALUBusy).
// ---------------------------------------------------------------------------
__global__ __launch_bounds__(512) void mix_kernel(
        const float* __restrict__ Sbuf, const float* __restrict__ pitch,
        const float* __restrict__ amp, const float* __restrict__ att,
        const float* __restrict__ wtg, float* __restrict__ out, int ntiles) {
    __shared__ float wt_lds[WT_LEN * N_WT];    // [i][c], 40 KB
    __shared__ float att_lds[512 * N_WT];      // 8 wave slices x (64 elems x 20), 40 KB
    const int tid  = threadIdx.x;
    const int lane = tid & 63;
    const int w    = tid >> 6;

    for (int e = tid; e < WT_LEN * N_WT; e += 512) {
        int c = e >> 9;               // wtg is [N_WT][WT_LEN]
        int i = e & (WT_LEN - 1);
        float v = wtg[e];
        if (c >= 4) v = tanhf(v);
        wt_lds[i * N_WT + c] = v;
    }
    __syncthreads();                  // only barrier: wt table publication

    float4* slice4 = (float4*)(att_lds + w * (64 * N_WT));   // this wave's slice
    const float* my_att = att_lds + (w * 64 + lane) * N_WT;  // this lane's element

    for (int tile = blockIdx.x; tile < ntiles; tile += gridDim.x) {
        const int gbase = tile * 512;                 // tile is row-aligned (T_%512==0)
        const int row   = gbase >> 18;
        const float x0row = to_inc1(pitch[(size_t)row << 18]);

        const int ebase = gbase + w * 64;             // this wave's 64 elements
        const int gid   = ebase + lane;

        // stage att micro-tile: 320 float4, lane-coalesced (16 B lane stride)
        const float4* g4 = (const float4*)(att + (size_t)ebase * N_WT);
#pragma unroll
        for (int v = 0; v < 5; ++v)
            slice4[v * 64 + lane] = g4[v * 64 + lane];

        float S = Sbuf[gid];
        float y = S - x0row;              // index = cumsum - increment[:, :1]

        // exact fmod(y, 512)
        float qf  = floorf(y * (1.0f / 512.0f));
        float idx = fmaf(-512.0f, qf, y);
        if (idx < 0.0f)    idx += 512.0f;
        if (idx >= 512.0f) idx -= 512.0f;

        float fl0   = floorf(idx);
        float alpha = idx - fl0;
        int il = ((int)fl0) & (WT_LEN - 1);
        int ih = (il + (alpha > 0.0f ? 1 : 0)) & (WT_LEN - 1);

        const float4* lo4 = (const float4*)(&wt_lds[il * N_WT]);
        const float4* hi4 = (const float4*)(&wt_lds[ih * N_WT]);
        const float4* a4  = (const float4*)my_att;

        float acc = 0.0f;
#pragma unroll
        for (int v = 0; v < 5; ++v) {
            float4 lo = lo4[v];
            float4 hi = hi4[v];
            float4 at = a4[v];
            acc += at.x * (lo.x + alpha * (hi.x - lo.x));
            acc += at.y * (lo.y + alpha * (hi.y - lo.y));
            acc += at.z * (lo.z + alpha * (hi.z - lo.z));
            acc += at.w * (lo.w + alpha * (hi.w - lo.w));
        }
        out[gid] = acc * amp[gid];
    }
}

// ---------------------------------------------------------------------------
extern "C" void kernel_launch(void* const* d_in, const int* in_sizes, int n_in,
                              void* d_out, int out_size, void* d_ws, size_t ws_size,
                              hipStream_t stream) {
    const float* pitch = (const float*)d_in[0];
    const float* amp   = (const float*)d_in[1];
    const float* att   = (const float*)d_in[2];
    const float* wtg   = (const float*)d_in[3];

    float* A13 = (float*)d_ws;          // [512]
    float* S   = A13 + 1024;            // [TOTAL], 4 KB-aligned

    up_kernel<<<NCH, 1024, 0, stream>>>(pitch, A13);
    down_kernel<<<NCH, 1024, 0, stream>>>(pitch, A13, S);
    mix_kernel<<<1024, 512, 0, stream>>>(S, pitch, amp, att, wtg,
                                         (float*)d_out, TOTAL / 512);
    // DIAGNOSTIC (this round only): same work at grid 256 -> ~4x duration,
    // forces a mix_kernel row into rocprof's top-5. Output bytes identical.
    mix_kernel<<<256, 512, 0, stream>>>(S, pitch, amp, att, wtg,
                                        (float*)d_out, TOTAL / 512);
}